// Round 17
// baseline (11673.123 us; speedup 1.0000x reference)
//
#include <hip/hip_runtime.h>
#include <hip/hip_bf16.h>

#define S_LEN 2048
#define BATCH 64
#define HID   512
#define GATES 2048   // 4*HID
#define DIN   512

typedef __attribute__((ext_vector_type(8))) short short8v;
typedef __attribute__((ext_vector_type(4))) float f32x4;
typedef __attribute__((ext_vector_type(4))) unsigned uint4v;

__device__ inline unsigned short f2bf(float f) {
  union { float f; unsigned u; } a; a.f = f;
  unsigned r = a.u + 0x7fffu + ((a.u >> 16) & 1u);
  return (unsigned short)(r >> 16);
}
__device__ inline float bf2f(unsigned short h) {
  union { unsigned u; float f; } a; a.u = ((unsigned)h) << 16; return a.f;
}

// ---------- kernel 1: split x (fp32) -> bf16 hi + lo ----------
__global__ __launch_bounds__(256) void k_split_x(const float* __restrict__ x,
                                                 unsigned short* __restrict__ xhi,
                                                 unsigned short* __restrict__ xlo) {
  const long total = (long)S_LEN * BATCH * DIN / 4;
  long i = (long)blockIdx.x * blockDim.x + threadIdx.x;
  const long stride = (long)gridDim.x * blockDim.x;
  for (; i < total; i += stride) {
    float4 v = ((const float4*)x)[i];
    ushort4 hv, lv;
    hv.x = f2bf(v.x); lv.x = f2bf(v.x - bf2f(hv.x));
    hv.y = f2bf(v.y); lv.y = f2bf(v.y - bf2f(hv.y));
    hv.z = f2bf(v.z); lv.z = f2bf(v.z - bf2f(hv.z));
    hv.w = f2bf(v.w); lv.w = f2bf(v.w - bf2f(hv.w));
    ((ushort4*)xhi)[i] = hv;
    ((ushort4*)xlo)[i] = lv;
  }
}

// ---------- kernel 2: weights -> bf16, bias sum ----------
__global__ __launch_bounds__(256) void k_prep_w(const float* __restrict__ Wih,
                                                const float* __restrict__ Whh,
                                                const float* __restrict__ bih,
                                                const float* __restrict__ bhh,
                                                unsigned short* __restrict__ WihB,
                                                unsigned short* __restrict__ WhhB,
                                                float* __restrict__ bias) {
  int i = blockIdx.x * 256 + threadIdx.x;
  if (i < GATES * DIN) {
    WihB[i] = f2bf(Wih[i]);
    WhhB[i] = f2bf(Whh[i]);
  }
  if (i < GATES) bias[i] = bih[i] + bhh[i];
}

// ---------- kernel 3: pre[t][u][b][gate] = x[t,b,:]·Wih[gate*512+u,:] + biases ----------
#define BM 128
#define BN 128
#define BK 32
#define LDSROW 40

__global__ __launch_bounds__(256) void k_gemm_pre(
    const unsigned short* __restrict__ A,   // WihB [2048][512]
    const unsigned short* __restrict__ Bh,  // xhi  [131072][512]
    const unsigned short* __restrict__ Bl,  // xlo
    const float* __restrict__ bias,
    unsigned short* __restrict__ pre)       // [S][512 u][64 b][4 gate] bf16
{
  __shared__ unsigned short As [BM * LDSROW];
  __shared__ unsigned short Bhs[BM * LDSROW];
  __shared__ unsigned short Bls[BM * LDSROW];

  const int tid  = threadIdx.x;
  const int lane = tid & 63;
  const int wave = tid >> 6;
  const int bm = blockIdx.x & 15;
  const int bn = blockIdx.x >> 4;
  const int wr = wave >> 1, wc = wave & 1;

  f32x4 acc[4][4];
  #pragma unroll
  for (int i = 0; i < 4; ++i)
    #pragma unroll
    for (int j = 0; j < 4; ++j) acc[i][j] = (f32x4){0.f, 0.f, 0.f, 0.f};

  const long arow0 = (long)bm * BM;
  const long brow0 = (long)bn * BN;

  for (int kt = 0; kt < DIN / BK; ++kt) {
    #pragma unroll
    for (int it = 0; it < 2; ++it) {
      int c = tid + it * 256;
      int row = c >> 2, kc = c & 3;
      int lbyte = row * (LDSROW * 2) + kc * 16;
      long ga = (arow0 + row) * 512 + kt * BK + kc * 8;
      long gb = (brow0 + row) * 512 + kt * BK + kc * 8;
      *(short8v*)((char*)As  + lbyte) = *(const short8v*)(A  + ga);
      *(short8v*)((char*)Bhs + lbyte) = *(const short8v*)(Bh + gb);
      *(short8v*)((char*)Bls + lbyte) = *(const short8v*)(Bl + gb);
    }
    __syncthreads();

    short8v a[4], bh[4], bl[4];
    #pragma unroll
    for (int mt = 0; mt < 4; ++mt) {
      int r = wr * 64 + mt * 16 + (lane & 15);
      a[mt] = *(const short8v*)((const char*)As + r * (LDSROW * 2) + (lane >> 4) * 16);
    }
    #pragma unroll
    for (int nt = 0; nt < 4; ++nt) {
      int r = wc * 64 + nt * 16 + (lane & 15);
      bh[nt] = *(const short8v*)((const char*)Bhs + r * (LDSROW * 2) + (lane >> 4) * 16);
      bl[nt] = *(const short8v*)((const char*)Bls + r * (LDSROW * 2) + (lane >> 4) * 16);
    }
    #pragma unroll
    for (int mt = 0; mt < 4; ++mt)
      #pragma unroll
      for (int nt = 0; nt < 4; ++nt) {
        acc[mt][nt] = __builtin_amdgcn_mfma_f32_16x16x32_bf16(a[mt], bh[nt], acc[mt][nt], 0, 0, 0);
        acc[mt][nt] = __builtin_amdgcn_mfma_f32_16x16x32_bf16(a[mt], bl[nt], acc[mt][nt], 0, 0, 0);
      }
    __syncthreads();
  }

  #pragma unroll
  for (int mt = 0; mt < 4; ++mt) {
    #pragma unroll
    for (int j = 0; j < 4; ++j) {
      int m = bm * BM + wr * 64 + mt * 16 + (lane >> 4) * 4 + j;
      int gate = m >> 9;
      int u    = m & 511;
      float bv = bias[m];
      #pragma unroll
      for (int nt = 0; nt < 4; ++nt) {
        int n = bn * BN + wc * 64 + nt * 16 + (lane & 15);
        int t = n >> 6, b = n & 63;
        pre[(((long)t * 512 + u) * 64 + b) * 4 + gate] = f2bf(acc[mt][nt][j] + bv);
      }
    }
  }
}

// ---------- kernel 4: persistent recurrence, per-wave flags, 1 barrier/step ----------
// r15 machine (64 blocks x 512 threads, 8 gate-complete tiles, W_hh 128KB LDS,
// swizzled ldsH, u64-tagged h, plain-first + validated-atomic-retry gather)
// with the publish path DE-COUPLED:
//  * flags are PER-WAVE ([4 quads][16 blocks][8 waves]). Each wave drains its
//    OWN publish stores (vmcnt(0)) then posts its flag — no block-wide
//    __syncthreads on the publish path, no slowest-wave coupling.
//  * bar2 deleted: the ldsH WAR (step-t MFMA reads vs t+1 staging writes) is
//    ordered by discovery — consumers poll ALL 128 quad flags INCLUDING their
//    own block's waves, so wave B stages t+1 only after wave A posted
//    flag(t+1), which A does only after its step-t ldsH reads completed.
//  * hbuf phase-reuse causality unchanged: flag(t+1) from every wave ==> its
//    block passed bar1 of step t ==> its gather of phase t&1 completed ==>
//    publishing h(t+2) into phase t&1 is safe. Tag validation (r14/r15)
//    remains as the belt-and-braces against flag-beats-data reordering.
// Net: 1 barrier/step (bar1) instead of 3.
__global__ __launch_bounds__(512, 1) void k_lstm(
    const unsigned short* __restrict__ pre,   // [S][512][64][4] bf16
    const unsigned short* __restrict__ WhhB,  // [2048][512] bf16
    unsigned long long* __restrict__ hbuf,    // [2][64 b][256] u64 (2 units | tag)
    unsigned* __restrict__ flags,             // [4][16][8] per-wave
    float* __restrict__ out)                  // [S*B*H | h_f | c_f]
{
  __shared__ char lds[147456];
  char* ldsW = lds;            // 128KB [ct:8][ks:16][ke:4][r:16][16B]
  char* ldsH = lds + 131072;   // 16KB  [ke:4][b:16][slot:16][16B], slot=(ks^b)&15

  const int tid  = threadIdx.x;
  const int lane = tid & 63;
  const int wave = tid >> 6;          // 0..7 == tile ct
  const int q    = blockIdx.x >> 4;   // batch quad
  const int ublk = blockIdx.x & 15;   // unit 32-block

  // --- stage W tile into LDS (once): tile-row r -> (du = r>>2, gate = r&3) ---
  for (int c = tid; c < 8192; c += 512) {
    int ct2 = c >> 10, r6 = c & 1023;
    int ks = r6 >> 6, ke = (r6 >> 4) & 3, r = r6 & 15;
    long row = (long)(r & 3) * 512 + ublk * 32 + ct2 * 4 + (r >> 2);
    *(short8v*)(ldsW + c * 16) =
        *(const short8v*)(WhhB + row * 512 + ks * 32 + ke * 8);
  }
  __syncthreads();

  // gather assignment: thread stages 16 units (8 tagged u64, 64B) for one row
  const int gb  = tid >> 5;           // 0..15 (batch row staged)
  const int us  = tid & 31;           // 0..31
  const int gks = us >> 1;            // k-step (32 units)
  const int keh = us & 1;             // which 16-unit half

  // cell assignment: one cell per lane, tile ct = wave
  const int ct  = wave;
  const int b_c = lane & 15;
  const int duc = lane >> 4;
  const int b_g = q * 16 + b_c;
  const int u_g = ublk * 32 + ct * 4 + duc;

  float cst = 0.f;
  float heat = (float)tid * 1e-3f + 1.0f;

  #pragma unroll 1
  for (int t = 0; t < S_LEN; ++t) {
    // x-gates (8B, i/f/g/o contiguous) — issued before the poll, hides under it
    ushort4 pv = *(const ushort4*)(pre + (((long)t * 512 + u_g) * 64 + b_g) * 4);

    if (t > 0) {
      // discovery: 128 per-wave flags; each lane checks a u64 pair (1 packet)
      {
        const unsigned long long* fp =
            (const unsigned long long*)(flags + q * 128) + lane;
        while (true) {
          unsigned long long v = __hip_atomic_load(fp, __ATOMIC_RELAXED,
                                                   __HIP_MEMORY_SCOPE_AGENT);
          bool ok = ((unsigned)v >= (unsigned)t) &&
                    ((unsigned)(v >> 32) >= (unsigned)t);
          if (__all(ok)) break;
          #pragma unroll
          for (int z = 0; z < 8; ++z) heat = __builtin_fmaf(heat, 1.000001f, 1e-6f);
          asm volatile("" : "+v"(heat));
        }
      }
      asm volatile("" ::: "memory");

      const unsigned long long* hb = hbuf + (t & 1) * (64 * 256)
                                   + (q * 16 + gb) * 256 + gks * 16 + keh * 8;
      const unsigned tg = (unsigned)t;
      unsigned long long w[8];
      // first try: 4 plain 16B loads (min packets; tags catch staleness)
      {
        ulonglong2 v0 = *(const ulonglong2*)(hb + 0);
        ulonglong2 v1 = *(const ulonglong2*)(hb + 2);
        ulonglong2 v2 = *(const ulonglong2*)(hb + 4);
        ulonglong2 v3 = *(const ulonglong2*)(hb + 6);
        w[0] = v0.x; w[1] = v0.y; w[2] = v1.x; w[3] = v1.y;
        w[4] = v2.x; w[5] = v2.y; w[6] = v3.x; w[7] = v3.y;
      }
      while (true) {
        unsigned bad = 0;
        #pragma unroll
        for (int j = 0; j < 8; ++j) bad |= ((unsigned)w[j]) ^ tg;
        if (__all(bad == 0)) break;
        // retry: coherent agent-atomic path (guaranteed fresh)
        #pragma unroll
        for (int j = 0; j < 8; ++j)
          w[j] = __hip_atomic_load(hb + j, __ATOMIC_RELAXED, __HIP_MEMORY_SCOPE_AGENT);
      }
      // payload = hi32 of each u64 (2 packed bf16 units); 2 swizzled b128 writes
      char* hp = ldsH + gb * 256 + ((gks ^ gb) & 15) * 16;
      uint4v d0, d1;
      #pragma unroll
      for (int j = 0; j < 4; ++j) {
        d0[j] = (unsigned)(w[j]     >> 32);
        d1[j] = (unsigned)(w[4 + j] >> 32);
      }
      *(uint4v*)(hp + (keh * 2 + 0) * 4096) = d0;
      *(uint4v*)(hp + (keh * 2 + 1) * 4096) = d1;
    }

    // barrier #1 (the only block barrier per step): H tile ready
    asm volatile("s_waitcnt lgkmcnt(0)" ::: "memory");
    __builtin_amdgcn_s_barrier();
    __builtin_amdgcn_sched_barrier(0);

    f32x4 sum = (f32x4){0.f, 0.f, 0.f, 0.f};
    if (t > 0) {
      f32x4 e0 = sum, e1 = sum;
      const char* wa = ldsW + ct * 16384 + (lane >> 4) * 256 + (lane & 15) * 16;
      const char* ha = ldsH + (lane >> 4) * 4096 + (lane & 15) * 256;
      const int bcol = lane & 15;
      #pragma unroll
      for (int ks = 0; ks < 16; ++ks) {
        short8v av = *(const short8v*)(wa + ks * 1024);               // W (A-op)
        short8v bv = *(const short8v*)(ha + ((ks ^ bcol) & 15) * 16); // h (B-op)
        if (ks & 1) e1 = __builtin_amdgcn_mfma_f32_16x16x32_bf16(av, bv, e1, 0, 0, 0);
        else        e0 = __builtin_amdgcn_mfma_f32_16x16x32_bf16(av, bv, e0, 0, 0, 0);
      }
      sum = e0 + e1;
    }
    // ensure this wave's ldsH reads are complete before it may later re-stage
    asm volatile("s_waitcnt lgkmcnt(0)" ::: "memory");

    // cell update fully in-register: sum[0..3] = (i,f,g,o)
    float zi = sum[0] + bf2f(pv.x);
    float zf = sum[1] + bf2f(pv.y);
    float zg = sum[2] + bf2f(pv.z);
    float zo = sum[3] + bf2f(pv.w);
    float ii = 1.f / (1.f + __expf(-zi));
    float ff = 1.f / (1.f + __expf(-zf));
    float e1x = __expf(2.f * fminf(zg, 15.f));
    float gg = (e1x - 1.f) / (e1x + 1.f);
    float oo = 1.f / (1.f + __expf(-zo));
    float cn = ff * cst + ii * gg;
    float e2x = __expf(2.f * fminf(cn, 15.f));
    float tc = (e2x - 1.f) / (e2x + 1.f);
    float hv = oo * tc;
    cst = cn;

    // tagged publish: pair lanes pack 2 units + step tag into one u64 store
    {
      unsigned short h16 = f2bf(hv);
      unsigned prt = (unsigned)__shfl_xor((int)(unsigned)h16, 16);
      if (!(lane & 16)) {   // duc even: lo16 = unit u, hi16 = unit u+1
        unsigned payload = (unsigned)h16 | (prt << 16);
        unsigned long long w64 = ((unsigned long long)payload << 32)
                               | (unsigned)(t + 1);
        __hip_atomic_store(hbuf + ((t + 1) & 1) * (64 * 256) + b_g * 256
                               + ublk * 16 + ct * 2 + (duc >> 1),
                           w64, __ATOMIC_RELAXED, __HIP_MEMORY_SCOPE_AGENT);
      }
    }

    // per-WAVE release: drain own publish stores, post own flag. No block
    // barrier — wave-level truthfulness is all consumers need.
    asm volatile("s_waitcnt vmcnt(0)" ::: "memory");
    if (lane == 0)
      __hip_atomic_store(&flags[q * 128 + ublk * 8 + wave], (unsigned)(t + 1),
                         __ATOMIC_RELAXED, __HIP_MEMORY_SCOPE_AGENT);

    // out stores AFTER flag publish: off the critical path
    out[(long)t * (BATCH * HID) + (long)b_g * HID + u_g] = hv;
    if (t == S_LEN - 1) {
      long fb = (long)S_LEN * (BATCH * HID);
      out[fb + (long)b_g * HID + u_g] = hv;
      out[fb + BATCH * HID + (long)b_g * HID + u_g] = cn;
    }
  }
}

extern "C" void kernel_launch(void* const* d_in, const int* in_sizes, int n_in,
                              void* d_out, int out_size, void* d_ws, size_t ws_size,
                              hipStream_t stream) {
  const float* x   = (const float*)d_in[0];
  const float* Wih = (const float*)d_in[1];
  const float* Whh = (const float*)d_in[2];
  const float* bih = (const float*)d_in[3];
  const float* bhh = (const float*)d_in[4];
  float* out = (float*)d_out;

  char* ws = (char*)d_ws;
  size_t off = 0;
  auto alloc = [&](size_t bytes) -> char* {
    char* p = ws + off;
    off += (bytes + 255) & ~(size_t)255;
    return p;
  };
  unsigned short*     xhi  = (unsigned short*)alloc((size_t)S_LEN * BATCH * DIN * 2);
  unsigned short*     xlo  = (unsigned short*)alloc((size_t)S_LEN * BATCH * DIN * 2);
  unsigned short*     preb = (unsigned short*)alloc((size_t)S_LEN * GATES * BATCH * 2);
  unsigned short*     WihB = (unsigned short*)alloc((size_t)GATES * DIN * 2);
  unsigned short*     WhhB = (unsigned short*)alloc((size_t)GATES * DIN * 2);
  float*              bias = (float*)alloc((size_t)GATES * 4);
  unsigned long long* hbuf = (unsigned long long*)alloc((size_t)2 * 64 * 256 * 8); // 256KB
  unsigned*           flg  = (unsigned*)alloc((size_t)4 * 128 * 4);                // 2KB

  // replay-safe: clear tags + flags every launch
  hipMemsetAsync(hbuf, 0, (size_t)2 * 64 * 256 * 8, stream);
  hipMemsetAsync(flg, 0, (size_t)4 * 128 * 4, stream);
  k_split_x<<<8192, 256, 0, stream>>>(x, xhi, xlo);
  k_prep_w<<<4096, 256, 0, stream>>>(Wih, Whh, bih, bhh, WihB, WhhB, bias);
  k_gemm_pre<<<16384, 256, 0, stream>>>(WihB, xhi, xlo, bias, preb);
  k_lstm<<<64, 512, 0, stream>>>(preb, WhhB, hbuf, flg, out);
}

// Round 18
// 8997.426 us; speedup vs baseline: 1.2974x; 1.2974x over previous
//
#include <hip/hip_runtime.h>
#include <hip/hip_bf16.h>

#define S_LEN 2048
#define BATCH 64
#define HID   512
#define GATES 2048   // 4*HID
#define DIN   512

typedef __attribute__((ext_vector_type(8))) short short8v;
typedef __attribute__((ext_vector_type(4))) float f32x4;
typedef __attribute__((ext_vector_type(4))) unsigned uint4v;

__device__ inline unsigned short f2bf(float f) {
  union { float f; unsigned u; } a; a.f = f;
  unsigned r = a.u + 0x7fffu + ((a.u >> 16) & 1u);
  return (unsigned short)(r >> 16);
}
__device__ inline float bf2f(unsigned short h) {
  union { unsigned u; float f; } a; a.u = ((unsigned)h) << 16; return a.f;
}

// ---------- kernel 1: split x (fp32) -> bf16 hi + lo ----------
__global__ __launch_bounds__(256) void k_split_x(const float* __restrict__ x,
                                                 unsigned short* __restrict__ xhi,
                                                 unsigned short* __restrict__ xlo) {
  const long total = (long)S_LEN * BATCH * DIN / 4;
  long i = (long)blockIdx.x * blockDim.x + threadIdx.x;
  const long stride = (long)gridDim.x * blockDim.x;
  for (; i < total; i += stride) {
    float4 v = ((const float4*)x)[i];
    ushort4 hv, lv;
    hv.x = f2bf(v.x); lv.x = f2bf(v.x - bf2f(hv.x));
    hv.y = f2bf(v.y); lv.y = f2bf(v.y - bf2f(hv.y));
    hv.z = f2bf(v.z); lv.z = f2bf(v.z - bf2f(hv.z));
    hv.w = f2bf(v.w); lv.w = f2bf(v.w - bf2f(hv.w));
    ((ushort4*)xhi)[i] = hv;
    ((ushort4*)xlo)[i] = lv;
  }
}

// ---------- kernel 2: weights -> bf16, bias sum ----------
__global__ __launch_bounds__(256) void k_prep_w(const float* __restrict__ Wih,
                                                const float* __restrict__ Whh,
                                                const float* __restrict__ bih,
                                                const float* __restrict__ bhh,
                                                unsigned short* __restrict__ WihB,
                                                unsigned short* __restrict__ WhhB,
                                                float* __restrict__ bias) {
  int i = blockIdx.x * 256 + threadIdx.x;
  if (i < GATES * DIN) {
    WihB[i] = f2bf(Wih[i]);
    WhhB[i] = f2bf(Whh[i]);
  }
  if (i < GATES) bias[i] = bih[i] + bhh[i];
}

// ---------- kernel 3: pre[t][u][b][gate] = x[t,b,:]·Wih[gate*512+u,:] + biases ----------
#define BM 128
#define BN 128
#define BK 32
#define LDSROW 40

__global__ __launch_bounds__(256) void k_gemm_pre(
    const unsigned short* __restrict__ A,   // WihB [2048][512]
    const unsigned short* __restrict__ Bh,  // xhi  [131072][512]
    const unsigned short* __restrict__ Bl,  // xlo
    const float* __restrict__ bias,
    unsigned short* __restrict__ pre)       // [S][512 u][64 b][4 gate] bf16
{
  __shared__ unsigned short As [BM * LDSROW];
  __shared__ unsigned short Bhs[BM * LDSROW];
  __shared__ unsigned short Bls[BM * LDSROW];

  const int tid  = threadIdx.x;
  const int lane = tid & 63;
  const int wave = tid >> 6;
  const int bm = blockIdx.x & 15;
  const int bn = blockIdx.x >> 4;
  const int wr = wave >> 1, wc = wave & 1;

  f32x4 acc[4][4];
  #pragma unroll
  for (int i = 0; i < 4; ++i)
    #pragma unroll
    for (int j = 0; j < 4; ++j) acc[i][j] = (f32x4){0.f, 0.f, 0.f, 0.f};

  const long arow0 = (long)bm * BM;
  const long brow0 = (long)bn * BN;

  for (int kt = 0; kt < DIN / BK; ++kt) {
    #pragma unroll
    for (int it = 0; it < 2; ++it) {
      int c = tid + it * 256;
      int row = c >> 2, kc = c & 3;
      int lbyte = row * (LDSROW * 2) + kc * 16;
      long ga = (arow0 + row) * 512 + kt * BK + kc * 8;
      long gb = (brow0 + row) * 512 + kt * BK + kc * 8;
      *(short8v*)((char*)As  + lbyte) = *(const short8v*)(A  + ga);
      *(short8v*)((char*)Bhs + lbyte) = *(const short8v*)(Bh + gb);
      *(short8v*)((char*)Bls + lbyte) = *(const short8v*)(Bl + gb);
    }
    __syncthreads();

    short8v a[4], bh[4], bl[4];
    #pragma unroll
    for (int mt = 0; mt < 4; ++mt) {
      int r = wr * 64 + mt * 16 + (lane & 15);
      a[mt] = *(const short8v*)((const char*)As + r * (LDSROW * 2) + (lane >> 4) * 16);
    }
    #pragma unroll
    for (int nt = 0; nt < 4; ++nt) {
      int r = wc * 64 + nt * 16 + (lane & 15);
      bh[nt] = *(const short8v*)((const char*)Bhs + r * (LDSROW * 2) + (lane >> 4) * 16);
      bl[nt] = *(const short8v*)((const char*)Bls + r * (LDSROW * 2) + (lane >> 4) * 16);
    }
    #pragma unroll
    for (int mt = 0; mt < 4; ++mt)
      #pragma unroll
      for (int nt = 0; nt < 4; ++nt) {
        acc[mt][nt] = __builtin_amdgcn_mfma_f32_16x16x32_bf16(a[mt], bh[nt], acc[mt][nt], 0, 0, 0);
        acc[mt][nt] = __builtin_amdgcn_mfma_f32_16x16x32_bf16(a[mt], bl[nt], acc[mt][nt], 0, 0, 0);
      }
    __syncthreads();
  }

  #pragma unroll
  for (int mt = 0; mt < 4; ++mt) {
    #pragma unroll
    for (int j = 0; j < 4; ++j) {
      int m = bm * BM + wr * 64 + mt * 16 + (lane >> 4) * 4 + j;
      int gate = m >> 9;
      int u    = m & 511;
      float bv = bias[m];
      #pragma unroll
      for (int nt = 0; nt < 4; ++nt) {
        int n = bn * BN + wc * 64 + nt * 16 + (lane & 15);
        int t = n >> 6, b = n & 63;
        pre[(((long)t * 512 + u) * 64 + b) * 4 + gate] = f2bf(acc[mt][nt][j] + bv);
      }
    }
  }
}

// ---------- kernel 4: persistent recurrence, u64-tagged verified gather ----------
// The round-15 champion, verbatim. 64 blocks x 512 threads; quad q = bid>>4
// owns batches [q*16,+16); ublk = bid&15 owns units [ublk*32,+32). Wave ct
// computes one gate-complete 16x16 tile (acc[0..3] = i,f,g,o of one cell —
// swapped-MFMA, no transpose, no K-split). W_hh 128KB in LDS; ldsH 16KB
// XOR-swizzled. Sync: u64-tagged h ((2xbf16)<<32 | step), publish -> vmcnt
// drain -> __syncthreads -> per-block flag; discovery = 16 flags (1/lane);
// gather = 4 plain 16B loads first try, tag-VALIDATED, agent-atomic retry.
// Every protocol deviation tried (r11/r12/r14/r16/r17) regressed; this is
// the measured optimum: ~3.9us/step = ~3 MALL RTs + ~1us compute.
__global__ __launch_bounds__(512, 1) void k_lstm(
    const unsigned short* __restrict__ pre,   // [S][512][64][4] bf16
    const unsigned short* __restrict__ WhhB,  // [2048][512] bf16
    unsigned long long* __restrict__ hbuf,    // [2][64 b][256] u64 (2 units | tag)
    unsigned* __restrict__ flags,             // [4][16]
    float* __restrict__ out)                  // [S*B*H | h_f | c_f]
{
  __shared__ char lds[147456];
  char* ldsW = lds;            // 128KB [ct:8][ks:16][ke:4][r:16][16B]
  char* ldsH = lds + 131072;   // 16KB  [ke:4][b:16][slot:16][16B], slot=(ks^b)&15

  const int tid  = threadIdx.x;
  const int lane = tid & 63;
  const int wave = tid >> 6;          // 0..7 == tile ct
  const int q    = blockIdx.x >> 4;   // batch quad
  const int ublk = blockIdx.x & 15;   // unit 32-block

  // --- stage W tile into LDS (once): tile-row r -> (du = r>>2, gate = r&3) ---
  for (int c = tid; c < 8192; c += 512) {
    int ct2 = c >> 10, r6 = c & 1023;
    int ks = r6 >> 6, ke = (r6 >> 4) & 3, r = r6 & 15;
    long row = (long)(r & 3) * 512 + ublk * 32 + ct2 * 4 + (r >> 2);
    *(short8v*)(ldsW + c * 16) =
        *(const short8v*)(WhhB + row * 512 + ks * 32 + ke * 8);
  }
  __syncthreads();

  // gather assignment: thread stages 16 units (8 tagged u64, 64B) for one row
  const int gb  = tid >> 5;           // 0..15 (batch row staged)
  const int us  = tid & 31;           // 0..31
  const int gks = us >> 1;            // k-step (32 units)
  const int keh = us & 1;             // which 16-unit half

  // cell assignment: one cell per lane, tile ct = wave
  const int ct  = wave;
  const int b_c = lane & 15;
  const int duc = lane >> 4;
  const int b_g = q * 16 + b_c;
  const int u_g = ublk * 32 + ct * 4 + duc;

  float cst = 0.f;
  float heat = (float)tid * 1e-3f + 1.0f;

  #pragma unroll 1
  for (int t = 0; t < S_LEN; ++t) {
    // x-gates (8B, i/f/g/o contiguous) — issued before the poll, hides under it
    ushort4 pv = *(const ushort4*)(pre + (((long)t * 512 + u_g) * 64 + b_g) * 4);

    if (t > 0) {
      // discovery: 16 flags, 1 dword per lane (own block exempt)
      {
        const unsigned* fp = &flags[q * 16 + (lane & 15)];
        while (true) {
          unsigned v = ((lane & 15) == ublk) ? 0xffffffffu
                     : __hip_atomic_load(fp, __ATOMIC_RELAXED, __HIP_MEMORY_SCOPE_AGENT);
          if (__all(v >= (unsigned)t)) break;
          #pragma unroll
          for (int z = 0; z < 8; ++z) heat = __builtin_fmaf(heat, 1.000001f, 1e-6f);
          asm volatile("" : "+v"(heat));
        }
      }
      asm volatile("" ::: "memory");

      const unsigned long long* hb = hbuf + (t & 1) * (64 * 256)
                                   + (q * 16 + gb) * 256 + gks * 16 + keh * 8;
      const unsigned tg = (unsigned)t;
      unsigned long long w[8];
      // first try: 4 plain 16B loads (r13 packet count; tags catch staleness)
      {
        ulonglong2 v0 = *(const ulonglong2*)(hb + 0);
        ulonglong2 v1 = *(const ulonglong2*)(hb + 2);
        ulonglong2 v2 = *(const ulonglong2*)(hb + 4);
        ulonglong2 v3 = *(const ulonglong2*)(hb + 6);
        w[0] = v0.x; w[1] = v0.y; w[2] = v1.x; w[3] = v1.y;
        w[4] = v2.x; w[5] = v2.y; w[6] = v3.x; w[7] = v3.y;
      }
      while (true) {
        unsigned bad = 0;
        #pragma unroll
        for (int j = 0; j < 8; ++j) bad |= ((unsigned)w[j]) ^ tg;
        if (__all(bad == 0)) break;
        // retry: coherent agent-atomic path (L1/L2-bypassing, proven fresh)
        #pragma unroll
        for (int j = 0; j < 8; ++j)
          w[j] = __hip_atomic_load(hb + j, __ATOMIC_RELAXED, __HIP_MEMORY_SCOPE_AGENT);
      }
      // payload = hi32 of each u64 (2 packed bf16 units); 2 swizzled b128 writes
      char* hp = ldsH + gb * 256 + ((gks ^ gb) & 15) * 16;
      uint4v d0, d1;
      #pragma unroll
      for (int j = 0; j < 4; ++j) {
        d0[j] = (unsigned)(w[j]     >> 32);
        d1[j] = (unsigned)(w[4 + j] >> 32);
      }
      *(uint4v*)(hp + (keh * 2 + 0) * 4096) = d0;
      *(uint4v*)(hp + (keh * 2 + 1) * 4096) = d1;
    }

    // barrier #1: H tile ready (LDS-only drain)
    asm volatile("s_waitcnt lgkmcnt(0)" ::: "memory");
    __builtin_amdgcn_s_barrier();
    __builtin_amdgcn_sched_barrier(0);

    f32x4 sum = (f32x4){0.f, 0.f, 0.f, 0.f};
    if (t > 0) {
      f32x4 e0 = sum, e1 = sum;
      const char* wa = ldsW + ct * 16384 + (lane >> 4) * 256 + (lane & 15) * 16;
      const char* ha = ldsH + (lane >> 4) * 4096 + (lane & 15) * 256;
      const int bcol = lane & 15;
      #pragma unroll
      for (int ks = 0; ks < 16; ++ks) {
        short8v av = *(const short8v*)(wa + ks * 1024);               // W (A-op)
        short8v bv = *(const short8v*)(ha + ((ks ^ bcol) & 15) * 16); // h (B-op)
        if (ks & 1) e1 = __builtin_amdgcn_mfma_f32_16x16x32_bf16(av, bv, e1, 0, 0, 0);
        else        e0 = __builtin_amdgcn_mfma_f32_16x16x32_bf16(av, bv, e0, 0, 0, 0);
      }
      sum = e0 + e1;
    }

    // barrier #2: ldsH reads of step t done -> next staging may overwrite
    asm volatile("s_waitcnt lgkmcnt(0)" ::: "memory");
    __builtin_amdgcn_s_barrier();
    __builtin_amdgcn_sched_barrier(0);

    // cell update fully in-register: sum[0..3] = (i,f,g,o)
    float zi = sum[0] + bf2f(pv.x);
    float zf = sum[1] + bf2f(pv.y);
    float zg = sum[2] + bf2f(pv.z);
    float zo = sum[3] + bf2f(pv.w);
    float ii = 1.f / (1.f + __expf(-zi));
    float ff = 1.f / (1.f + __expf(-zf));
    float e1x = __expf(2.f * fminf(zg, 15.f));
    float gg = (e1x - 1.f) / (e1x + 1.f);
    float oo = 1.f / (1.f + __expf(-zo));
    float cn = ff * cst + ii * gg;
    float e2x = __expf(2.f * fminf(cn, 15.f));
    float tc = (e2x - 1.f) / (e2x + 1.f);
    float hv = oo * tc;
    cst = cn;

    // tagged publish: pair lanes pack 2 units + step tag into one u64 store
    {
      unsigned short h16 = f2bf(hv);
      unsigned prt = (unsigned)__shfl_xor((int)(unsigned)h16, 16);
      if (!(lane & 16)) {   // duc even: lo16 = unit u, hi16 = unit u+1
        unsigned payload = (unsigned)h16 | (prt << 16);
        unsigned long long w64 = ((unsigned long long)payload << 32)
                               | (unsigned)(t + 1);
        __hip_atomic_store(hbuf + ((t + 1) & 1) * (64 * 256) + b_g * 256
                               + ublk * 16 + ct * 2 + (duc >> 1),
                           w64, __ATOMIC_RELAXED, __HIP_MEMORY_SCOPE_AGENT);
      }
    }

    // release: drain h stores, then publish flag (fast-path discovery)
    asm volatile("s_waitcnt vmcnt(0)" ::: "memory");
    __syncthreads();
    if (tid == 0)
      __hip_atomic_store(&flags[q * 16 + ublk], (unsigned)(t + 1),
                         __ATOMIC_RELAXED, __HIP_MEMORY_SCOPE_AGENT);

    // out stores AFTER flag publish: off the critical path
    out[(long)t * (BATCH * HID) + (long)b_g * HID + u_g] = hv;
    if (t == S_LEN - 1) {
      long fb = (long)S_LEN * (BATCH * HID);
      out[fb + (long)b_g * HID + u_g] = hv;
      out[fb + BATCH * HID + (long)b_g * HID + u_g] = cn;
    }
  }
}

extern "C" void kernel_launch(void* const* d_in, const int* in_sizes, int n_in,
                              void* d_out, int out_size, void* d_ws, size_t ws_size,
                              hipStream_t stream) {
  const float* x   = (const float*)d_in[0];
  const float* Wih = (const float*)d_in[1];
  const float* Whh = (const float*)d_in[2];
  const float* bih = (const float*)d_in[3];
  const float* bhh = (const float*)d_in[4];
  float* out = (float*)d_out;

  char* ws = (char*)d_ws;
  size_t off = 0;
  auto alloc = [&](size_t bytes) -> char* {
    char* p = ws + off;
    off += (bytes + 255) & ~(size_t)255;
    return p;
  };
  unsigned short*     xhi  = (unsigned short*)alloc((size_t)S_LEN * BATCH * DIN * 2);
  unsigned short*     xlo  = (unsigned short*)alloc((size_t)S_LEN * BATCH * DIN * 2);
  unsigned short*     preb = (unsigned short*)alloc((size_t)S_LEN * GATES * BATCH * 2);
  unsigned short*     WihB = (unsigned short*)alloc((size_t)GATES * DIN * 2);
  unsigned short*     WhhB = (unsigned short*)alloc((size_t)GATES * DIN * 2);
  float*              bias = (float*)alloc((size_t)GATES * 4);
  unsigned long long* hbuf = (unsigned long long*)alloc((size_t)2 * 64 * 256 * 8); // 256KB
  unsigned*           flg  = (unsigned*)alloc((size_t)4 * 16 * 4);

  // replay-safe: clear tags + flags every launch
  hipMemsetAsync(hbuf, 0, (size_t)2 * 64 * 256 * 8, stream);
  hipMemsetAsync(flg, 0, (size_t)4 * 16 * 4, stream);
  k_split_x<<<8192, 256, 0, stream>>>(x, xhi, xlo);
  k_prep_w<<<4096, 256, 0, stream>>>(Wih, Whh, bih, bhh, WihB, WhhB, bias);
  k_gemm_pre<<<16384, 256, 0, stream>>>(WihB, xhi, xlo, bias, preb);
  k_lstm<<<64, 512, 0, stream>>>(preb, WhhB, hbuf, flg, out);
}